// Round 1
// baseline (3635.007 us; speedup 1.0000x reference)
//
#include <hip/hip_runtime.h>
#include <math.h>

#define B_ 4
#define N_ 2048
#define D_ 256
#define H_ 8
#define L_ 4
#define DH_ 32

// ---------------- proj: h = h_in * proj_w + proj_b (IN_DIM=1 outer product) ---
__global__ __launch_bounds__(256) void proj_kernel(
    const float* __restrict__ hin, const float* __restrict__ w,
    const float* __restrict__ bias, float* __restrict__ hout)
{
    long idx = (long)blockIdx.x * 256 + threadIdx.x;      // over B*N*64
    long bn = idx >> 6;
    int d4 = (int)(idx & 63) << 2;
    float hv = hin[bn];
    float4 wv = *(const float4*)&w[d4];
    float4 bv = *(const float4*)&bias[d4];
    float4 o;
    o.x = hv * wv.x + bv.x;
    o.y = hv * wv.y + bv.y;
    o.z = hv * wv.z + bv.z;
    o.w = hv * wv.w + bv.w;
    *(float4*)&hout[bn * D_ + d4] = o;
}

// ---------------- RoPE cos/sin table: per (b,n): [cos_t(8), sin_t(8), cos_x(8), sin_x(8)]
__global__ __launch_bounds__(256) void rope_table_kernel(
    const float* __restrict__ pos, float* __restrict__ tab)
{
    int i = blockIdx.x * 256 + threadIdx.x;   // over B*N = 8192
    if (i >= B_ * N_) return;
    float t = pos[i * 2 + 0] * 64.0f;
    float x = pos[i * 2 + 1] * 64.0f;
    float* o = tab + (long)i * 32;
    const float log2_1e4_over8 = 13.28771237954945f / 8.0f;
    #pragma unroll
    for (int j = 0; j < 8; ++j) {
        float invf = exp2f(-(float)j * log2_1e4_over8);   // 10000^{-j/8}
        float st, ct, sx, cx;
        sincosf(t * invf, &st, &ct);
        sincosf(x * invf, &sx, &cx);
        o[j]      = ct;
        o[8 + j]  = st;
        o[16 + j] = cx;
        o[24 + j] = sx;
    }
}

// ---------------- apply RoPE in-place to q and k sections of qkv -------------
// pairs (i, i+8) within each 16-half of the 32-dim head; halves use t / x angles
__global__ __launch_bounds__(256) void rope_apply_kernel(
    float* __restrict__ qkv, const float* __restrict__ tab)
{
    long idx = (long)blockIdx.x * 256 + threadIdx.x;  // B*N*H*16 = 2097152
    int p = (int)(idx & 15);
    int h = (int)((idx >> 4) & 7);
    long bn = idx >> 7;
    int half = p >> 3;
    int j = p & 7;
    const float* tb = tab + bn * 32;
    float c = tb[half * 16 + j];
    float s = tb[half * 16 + 8 + j];
    float* base = qkv + bn * (3 * D_) + h * DH_ + half * 16 + j;
    float u0 = base[0], u1 = base[8];
    base[0] = u0 * c - u1 * s;
    base[8] = u1 * c + u0 * s;
    float k0 = base[D_], k1 = base[D_ + 8];
    base[D_]     = k0 * c - k1 * s;
    base[D_ + 8] = k1 * c + k0 * s;
}

// ---------------- fp32 tiled GEMM: C = A(MxK) @ B(KxN) [+bias][relu] ---------
// 64x64 tile, BK=16, 256 threads, 4x4 per thread
__global__ __launch_bounds__(256) void gemm_f32(
    const float* __restrict__ A, const float* __restrict__ Bm,
    const float* __restrict__ bias, float* __restrict__ C,
    int M, int N, int K, int flags)
{
    __shared__ float sA[16][68];   // transposed A tile, padded (272B rows, 16B aligned)
    __shared__ float sB[16][64];
    int tid = threadIdx.x;
    int tx = tid & 15, ty = tid >> 4;
    int row0 = blockIdx.y * 64, col0 = blockIdx.x * 64;
    int arow = tid >> 2;
    int acol = (tid & 3) << 2;
    int brow = tid >> 4;
    int bcol = (tid & 15) << 2;
    const float* Aptr = A + (long)(row0 + arow) * K + acol;
    const float* Bptr = Bm + (long)brow * N + col0 + bcol;
    float acc[4][4] = {{0.f}};
    for (int kt = 0; kt < K; kt += 16) {
        float4 av = *(const float4*)(Aptr + kt);
        float4 bv = *(const float4*)(Bptr + (long)kt * N);
        __syncthreads();
        sA[acol + 0][arow] = av.x;
        sA[acol + 1][arow] = av.y;
        sA[acol + 2][arow] = av.z;
        sA[acol + 3][arow] = av.w;
        *(float4*)&sB[brow][bcol] = bv;
        __syncthreads();
        #pragma unroll
        for (int kk = 0; kk < 16; ++kk) {
            float4 a = *(const float4*)&sA[kk][ty << 2];
            float4 b = *(const float4*)&sB[kk][tx << 2];
            acc[0][0] += a.x * b.x; acc[0][1] += a.x * b.y; acc[0][2] += a.x * b.z; acc[0][3] += a.x * b.w;
            acc[1][0] += a.y * b.x; acc[1][1] += a.y * b.y; acc[1][2] += a.y * b.z; acc[1][3] += a.y * b.w;
            acc[2][0] += a.z * b.x; acc[2][1] += a.z * b.y; acc[2][2] += a.z * b.z; acc[2][3] += a.z * b.w;
            acc[3][0] += a.w * b.x; acc[3][1] += a.w * b.y; acc[3][2] += a.w * b.z; acc[3][3] += a.w * b.w;
        }
    }
    float4 bv4 = make_float4(0.f, 0.f, 0.f, 0.f);
    if (flags & 1) bv4 = *(const float4*)&bias[col0 + (tx << 2)];
    #pragma unroll
    for (int i = 0; i < 4; ++i) {
        int row = row0 + (ty << 2) + i;
        float4 o;
        o.x = acc[i][0] + bv4.x;
        o.y = acc[i][1] + bv4.y;
        o.z = acc[i][2] + bv4.z;
        o.w = acc[i][3] + bv4.w;
        if (flags & 2) {
            o.x = fmaxf(o.x, 0.f); o.y = fmaxf(o.y, 0.f);
            o.z = fmaxf(o.z, 0.f); o.w = fmaxf(o.w, 0.f);
        }
        *(float4*)&C[(long)row * N + col0 + (tx << 2)] = o;
    }
}

// ---------------- flash attention: 1 query row / thread, 64-key LDS tiles ----
__global__ __launch_bounds__(256) void attn_kernel(
    const float* __restrict__ qkv, float* __restrict__ o)
{
    int bh = blockIdx.y;
    int b = bh / H_, h = bh % H_;
    int n = blockIdx.x * 256 + threadIdx.x;     // row within batch
    const float* base = qkv + (long)b * N_ * (3 * D_);
    float q[DH_];
    #pragma unroll
    for (int d = 0; d < DH_; d += 4) {
        float4 v = *(const float4*)&base[(long)n * (3 * D_) + h * DH_ + d];
        q[d] = v.x; q[d + 1] = v.y; q[d + 2] = v.z; q[d + 3] = v.w;
    }
    float m = -1e30f, l = 0.f;
    float acc[DH_] = {0.f};
    __shared__ float sK[64][DH_];
    __shared__ float sV[64][DH_];
    const float scale = 0.17677669529663687f;   // 1/sqrt(32)
    for (int j0 = 0; j0 < N_; j0 += 64) {
        __syncthreads();
        int e = threadIdx.x;
        #pragma unroll
        for (int it = 0; it < 2; ++it, e += 256) {
            int r = e >> 3, c4 = (e & 7) << 2;
            *(float4*)&sK[r][c4] = *(const float4*)&base[(long)(j0 + r) * (3 * D_) + D_ + h * DH_ + c4];
            *(float4*)&sV[r][c4] = *(const float4*)&base[(long)(j0 + r) * (3 * D_) + 2 * D_ + h * DH_ + c4];
        }
        __syncthreads();
        for (int j = 0; j < 64; ++j) {
            float s = 0.f;
            #pragma unroll
            for (int d = 0; d < DH_; d += 4) {
                float4 kv = *(const float4*)&sK[j][d];
                s += q[d] * kv.x + q[d + 1] * kv.y + q[d + 2] * kv.z + q[d + 3] * kv.w;
            }
            s *= scale;
            if (s > m) {
                float corr = __expf(m - s);
                l *= corr;
                #pragma unroll
                for (int d = 0; d < DH_; ++d) acc[d] *= corr;
                m = s;
            }
            float p = __expf(s - m);
            l += p;
            #pragma unroll
            for (int d = 0; d < DH_; d += 4) {
                float4 vv = *(const float4*)&sV[j][d];
                acc[d] += p * vv.x; acc[d + 1] += p * vv.y;
                acc[d + 2] += p * vv.z; acc[d + 3] += p * vv.w;
            }
        }
    }
    float inv = 1.f / l;
    float* op = o + ((long)b * N_ + n) * D_ + h * DH_;
    #pragma unroll
    for (int d = 0; d < DH_; d += 4) {
        float4 v;
        v.x = acc[d] * inv; v.y = acc[d + 1] * inv;
        v.z = acc[d + 2] * inv; v.w = acc[d + 3] * inv;
        *(float4*)&op[d] = v;
    }
}

// ---------------- fused residual add + LayerNorm (row = 256, wave per row) ---
__global__ __launch_bounds__(256) void add_ln_kernel(
    float* __restrict__ h, const float* __restrict__ r,
    const float* __restrict__ g, const float* __restrict__ be)
{
    int row = blockIdx.x * 4 + (threadIdx.x >> 6);
    int lane = threadIdx.x & 63;
    long off = (long)row * D_ + (lane << 2);
    float4 x = *(float4*)&h[off];
    float4 rr = *(const float4*)&r[off];
    x.x += rr.x; x.y += rr.y; x.z += rr.z; x.w += rr.w;
    float s = x.x + x.y + x.z + x.w;
    #pragma unroll
    for (int k = 1; k < 64; k <<= 1) s += __shfl_xor(s, k, 64);
    float mean = s * (1.f / 256.f);
    float dx = x.x - mean, dy = x.y - mean, dz = x.z - mean, dw = x.w - mean;
    float sq = dx * dx + dy * dy + dz * dz + dw * dw;
    #pragma unroll
    for (int k = 1; k < 64; k <<= 1) sq += __shfl_xor(sq, k, 64);
    float rstd = rsqrtf(sq * (1.f / 256.f) + 1e-5f);
    float4 gv = *(const float4*)&g[lane << 2];
    float4 bv = *(const float4*)&be[lane << 2];
    float4 o;
    o.x = dx * rstd * gv.x + bv.x;
    o.y = dy * rstd * gv.y + bv.y;
    o.z = dz * rstd * gv.z + bv.z;
    o.w = dw * rstd * gv.w + bv.w;
    *(float4*)&h[off] = o;
}

extern "C" void kernel_launch(void* const* d_in, const int* in_sizes, int n_in,
                              void* d_out, int out_size, void* d_ws, size_t ws_size,
                              hipStream_t stream) {
    const float* h_in    = (const float*)d_in[0];
    const float* pos     = (const float*)d_in[1];
    const float* proj_w  = (const float*)d_in[2];
    const float* proj_b  = (const float*)d_in[3];
    const float* qkv_w   = (const float*)d_in[4];
    const float* out_w   = (const float*)d_in[5];
    const float* out_b   = (const float*)d_in[6];
    const float* O_w     = (const float*)d_in[7];
    const float* O_b     = (const float*)d_in[8];
    const float* ffn1_w  = (const float*)d_in[9];
    const float* ffn1_b  = (const float*)d_in[10];
    const float* ffn2_w  = (const float*)d_in[11];
    const float* ffn2_b  = (const float*)d_in[12];
    const float* ln1_g   = (const float*)d_in[13];
    const float* ln1_b   = (const float*)d_in[14];
    const float* ln2_g   = (const float*)d_in[15];
    const float* ln2_b   = (const float*)d_in[16];
    const float* final_w = (const float*)d_in[17];
    float* out = (float*)d_out;

    float* ws  = (float*)d_ws;
    float* h   = ws;                 // 2,097,152
    float* qkv = h + 2097152;        // 6,291,456
    float* ao  = qkv + 6291456;      // 2,097,152
    float* t1  = ao + 2097152;       // 2,097,152
    float* t2  = t1 + 2097152;       // 4,194,304
    float* tab = t2 + 4194304;       //   262,144

    const long M = (long)B_ * N_;    // 8192 rows

    proj_kernel<<<(M * 64) / 256, 256, 0, stream>>>(h_in, proj_w, proj_b, h);
    rope_table_kernel<<<(B_ * N_) / 256, 256, 0, stream>>>(pos, tab);

    for (int l = 0; l < L_; ++l) {
        // qkv = h @ qkv_w[l]   (8192x768, K=256, no bias)
        gemm_f32<<<dim3(768 / 64, M / 64), 256, 0, stream>>>(
            h, qkv_w + (long)l * D_ * 3 * D_, nullptr, qkv, M, 3 * D_, D_, 0);
        // RoPE on q and k
        rope_apply_kernel<<<(M * H_ * 16) / 256, 256, 0, stream>>>(qkv, tab);
        // flash attention -> ao
        attn_kernel<<<dim3(N_ / 256, B_ * H_), 256, 0, stream>>>(qkv, ao);
        // o @ out_w + out_b -> t1
        gemm_f32<<<dim3(D_ / 64, M / 64), 256, 0, stream>>>(
            ao, out_w + (long)l * D_ * D_, out_b + (long)l * D_, t1, M, D_, D_, 1);
        // t1 @ O_w + O_b -> t2
        gemm_f32<<<dim3(D_ / 64, M / 64), 256, 0, stream>>>(
            t1, O_w + (long)l * D_ * D_, O_b + (long)l * D_, t2, M, D_, D_, 1);
        // h = LN(h + t2)
        add_ln_kernel<<<M / 4, 256, 0, stream>>>(
            h, t2, ln1_g + (long)l * D_, ln1_b + (long)l * D_);
        // ffn1: relu(h @ ffn1_w + b) -> t2 (8192x512)
        gemm_f32<<<dim3(512 / 64, M / 64), 256, 0, stream>>>(
            h, ffn1_w + (long)l * D_ * 2 * D_, ffn1_b + (long)l * 2 * D_, t2, M, 2 * D_, D_, 3);
        // ffn2: t2 @ ffn2_w + b -> t1
        gemm_f32<<<dim3(D_ / 64, M / 64), 256, 0, stream>>>(
            t2, ffn2_w + (long)l * 2 * D_ * D_, ffn2_b + (long)l * D_, t1, M, D_, 2 * D_, 1);
        // h = LN(h + t1)
        add_ln_kernel<<<M / 4, 256, 0, stream>>>(
            h, t1, ln2_g + (long)l * D_, ln2_b + (long)l * D_);
    }
    // final: h @ final_w -> out (no bias)
    gemm_f32<<<dim3(D_ / 64, M / 64), 256, 0, stream>>>(
        h, final_w, nullptr, out, M, D_, D_, 0);
}

// Round 2
// 1246.294 us; speedup vs baseline: 2.9167x; 2.9167x over previous
//
#include <hip/hip_runtime.h>
#include <math.h>

#define B_ 4
#define N_ 2048
#define D_ 256
#define H_ 8
#define L_ 4
#define DH_ 32

typedef float f32x4 __attribute__((ext_vector_type(4)));
typedef short short8 __attribute__((ext_vector_type(8)));
typedef unsigned short ushort_t;

static __device__ __forceinline__ ushort_t f2bf(float x) {
    unsigned int u = __float_as_uint(x);
    unsigned int r = (u + 0x7fffu + ((u >> 16) & 1u)) >> 16;   // RNE
    return (ushort_t)r;
}

// ---------------- proj: h = h_in * proj_w + proj_b (IN_DIM=1 outer product) ---
__global__ __launch_bounds__(256) void proj_kernel(
    const float* __restrict__ hin, const float* __restrict__ w,
    const float* __restrict__ bias, float* __restrict__ hout)
{
    long idx = (long)blockIdx.x * 256 + threadIdx.x;      // over B*N*64
    long bn = idx >> 6;
    int d4 = (int)(idx & 63) << 2;
    float hv = hin[bn];
    float4 wv = *(const float4*)&w[d4];
    float4 bv = *(const float4*)&bias[d4];
    float4 o;
    o.x = hv * wv.x + bv.x;
    o.y = hv * wv.y + bv.y;
    o.z = hv * wv.z + bv.z;
    o.w = hv * wv.w + bv.w;
    *(float4*)&hout[bn * D_ + d4] = o;
}

// ---------------- RoPE cos/sin table: per (b,n): [cos_t(8), sin_t(8), cos_x(8), sin_x(8)]
__global__ __launch_bounds__(256) void rope_table_kernel(
    const float* __restrict__ pos, float* __restrict__ tab)
{
    int i = blockIdx.x * 256 + threadIdx.x;   // over B*N = 8192
    if (i >= B_ * N_) return;
    float t = pos[i * 2 + 0] * 64.0f;
    float x = pos[i * 2 + 1] * 64.0f;
    float* o = tab + (long)i * 32;
    const float log2_1e4_over8 = 13.28771237954945f / 8.0f;
    #pragma unroll
    for (int j = 0; j < 8; ++j) {
        float invf = exp2f(-(float)j * log2_1e4_over8);   // 10000^{-j/8}
        float st, ct, sx, cx;
        sincosf(t * invf, &st, &ct);
        sincosf(x * invf, &sx, &cx);
        o[j]      = ct;
        o[8 + j]  = st;
        o[16 + j] = cx;
        o[24 + j] = sx;
    }
}

// ---- RoPE + bf16 convert: qkv fp32 (B,N,3D) -> Qb,Kb (roped bf16), Vb bf16 --
// output layout (BH, N, 32) head-major
__global__ __launch_bounds__(256) void rope_convert_kernel(
    const float* __restrict__ qkv, const float* __restrict__ tab,
    ushort_t* __restrict__ Qb, ushort_t* __restrict__ Kb, ushort_t* __restrict__ Vb)
{
    long idx = (long)blockIdx.x * 256 + threadIdx.x;  // B*N*H*16 = 2097152
    int p = (int)(idx & 15);
    int h = (int)((idx >> 4) & 7);
    long bn = idx >> 7;
    int half = p >> 3;
    int j = p & 7;
    const float* tb = tab + bn * 32;
    float c = tb[half * 16 + j];
    float s = tb[half * 16 + 8 + j];
    int b = (int)(bn >> 11);
    int n = (int)(bn & 2047);
    long obase = ((long)(b * H_ + h) * N_ + n) * DH_;
    const float* base = qkv + bn * (3 * D_) + h * DH_ + half * 16 + j;
    int d0 = half * 16 + j;
    float q0 = base[0], q1 = base[8];
    Qb[obase + d0]     = f2bf(q0 * c - q1 * s);
    Qb[obase + d0 + 8] = f2bf(q1 * c + q0 * s);
    float k0 = base[D_], k1 = base[D_ + 8];
    Kb[obase + d0]     = f2bf(k0 * c - k1 * s);
    Kb[obase + d0 + 8] = f2bf(k1 * c + k0 * s);
    const float* vb = qkv + bn * (3 * D_) + 2 * D_ + h * DH_;
    Vb[obase + p]      = f2bf(vb[p]);
    Vb[obase + p + 16] = f2bf(vb[p + 16]);
}

// ---------------- fp32 tiled GEMM: C = A(MxK) @ B(KxN) [+bias][relu] ---------
__global__ __launch_bounds__(256) void gemm_f32(
    const float* __restrict__ A, const float* __restrict__ Bm,
    const float* __restrict__ bias, float* __restrict__ C,
    int M, int N, int K, int flags)
{
    __shared__ float sA[16][68];
    __shared__ float sB[16][64];
    int tid = threadIdx.x;
    int tx = tid & 15, ty = tid >> 4;
    int row0 = blockIdx.y * 64, col0 = blockIdx.x * 64;
    int arow = tid >> 2;
    int acol = (tid & 3) << 2;
    int brow = tid >> 4;
    int bcol = (tid & 15) << 2;
    const float* Aptr = A + (long)(row0 + arow) * K + acol;
    const float* Bptr = Bm + (long)brow * N + col0 + bcol;
    float acc[4][4] = {{0.f}};
    for (int kt = 0; kt < K; kt += 16) {
        float4 av = *(const float4*)(Aptr + kt);
        float4 bv = *(const float4*)(Bptr + (long)kt * N);
        __syncthreads();
        sA[acol + 0][arow] = av.x;
        sA[acol + 1][arow] = av.y;
        sA[acol + 2][arow] = av.z;
        sA[acol + 3][arow] = av.w;
        *(float4*)&sB[brow][bcol] = bv;
        __syncthreads();
        #pragma unroll
        for (int kk = 0; kk < 16; ++kk) {
            float4 a = *(const float4*)&sA[kk][ty << 2];
            float4 b = *(const float4*)&sB[kk][tx << 2];
            acc[0][0] += a.x * b.x; acc[0][1] += a.x * b.y; acc[0][2] += a.x * b.z; acc[0][3] += a.x * b.w;
            acc[1][0] += a.y * b.x; acc[1][1] += a.y * b.y; acc[1][2] += a.y * b.z; acc[1][3] += a.y * b.w;
            acc[2][0] += a.z * b.x; acc[2][1] += a.z * b.y; acc[2][2] += a.z * b.z; acc[2][3] += a.z * b.w;
            acc[3][0] += a.w * b.x; acc[3][1] += a.w * b.y; acc[3][2] += a.w * b.z; acc[3][3] += a.w * b.w;
        }
    }
    float4 bv4 = make_float4(0.f, 0.f, 0.f, 0.f);
    if (flags & 1) bv4 = *(const float4*)&bias[col0 + (tx << 2)];
    #pragma unroll
    for (int i = 0; i < 4; ++i) {
        int row = row0 + (ty << 2) + i;
        float4 o;
        o.x = acc[i][0] + bv4.x;
        o.y = acc[i][1] + bv4.y;
        o.z = acc[i][2] + bv4.z;
        o.w = acc[i][3] + bv4.w;
        if (flags & 2) {
            o.x = fmaxf(o.x, 0.f); o.y = fmaxf(o.y, 0.f);
            o.z = fmaxf(o.z, 0.f); o.w = fmaxf(o.w, 0.f);
        }
        *(float4*)&C[(long)row * N + col0 + (tx << 2)] = o;
    }
}

// ---------------- MFMA flash attention, bf16 inputs, fp32 softmax/accum ------
// grid (N/64, B*H), 256 threads (4 waves). Wave owns 16 q-rows; KV tile = 64.
__global__ __launch_bounds__(256) void attn_mfma(
    const ushort_t* __restrict__ Qb, const ushort_t* __restrict__ Kb,
    const ushort_t* __restrict__ Vb, float* __restrict__ o)
{
    const float SCALE = 0.17677669529663687f;   // 1/sqrt(32)
    int bh = blockIdx.y;
    int tid = threadIdx.x;
    int wid = tid >> 6, lane = tid & 63;
    int lo = lane & 15, hi = lane >> 4;
    int q0 = blockIdx.x * 64 + wid * 16;

    __shared__ ushort_t Vt[DH_][72];        // V transposed (dh, key), padded
    __shared__ ushort_t Pl[4][16][72];      // per-wave P (qrow, key), padded

    const ushort_t* Qbase = Qb + (long)bh * N_ * DH_;
    const ushort_t* Kbase = Kb + (long)bh * N_ * DH_;
    const ushort_t* Vbase = Vb + (long)bh * N_ * DH_;

    short8 qf = *(const short8*)&Qbase[(long)(q0 + lo) * DH_ + hi * 8];

    float mj[4], lj[4];
    f32x4 o0 = {0.f, 0.f, 0.f, 0.f}, o1 = {0.f, 0.f, 0.f, 0.f};
    #pragma unroll
    for (int j = 0; j < 4; ++j) { mj[j] = -1e30f; lj[j] = 0.f; }

    int vkey = tid & 63, vdh0 = (tid >> 6) * 8;

    for (int k0 = 0; k0 < N_; k0 += 64) {
        __syncthreads();
        // stage V transposed into LDS
        {
            short8 vv = *(const short8*)&Vbase[(long)(k0 + vkey) * DH_ + vdh0];
            #pragma unroll
            for (int jj = 0; jj < 8; ++jj) Vt[vdh0 + jj][vkey] = (ushort_t)vv[jj];
        }
        __syncthreads();

        // S = Q K^T for 16 q-rows x 64 keys (4 MFMAs)
        f32x4 zz = {0.f, 0.f, 0.f, 0.f};
        short8 kf0 = *(const short8*)&Kbase[(long)(k0 +  0 + lo) * DH_ + hi * 8];
        short8 kf1 = *(const short8*)&Kbase[(long)(k0 + 16 + lo) * DH_ + hi * 8];
        short8 kf2 = *(const short8*)&Kbase[(long)(k0 + 32 + lo) * DH_ + hi * 8];
        short8 kf3 = *(const short8*)&Kbase[(long)(k0 + 48 + lo) * DH_ + hi * 8];
        f32x4 s0 = __builtin_amdgcn_mfma_f32_16x16x32_bf16(qf, kf0, zz, 0, 0, 0);
        f32x4 s1 = __builtin_amdgcn_mfma_f32_16x16x32_bf16(qf, kf1, zz, 0, 0, 0);
        f32x4 s2 = __builtin_amdgcn_mfma_f32_16x16x32_bf16(qf, kf2, zz, 0, 0, 0);
        f32x4 s3 = __builtin_amdgcn_mfma_f32_16x16x32_bf16(qf, kf3, zz, 0, 0, 0);

        // online softmax (rows = hi*4+j, cols = keys: 4 tiles in-lane x 16 lanes)
        #pragma unroll
        for (int j = 0; j < 4; ++j) {
            float tm = fmaxf(fmaxf(s0[j], s1[j]), fmaxf(s2[j], s3[j]));
            #pragma unroll
            for (int d = 1; d < 16; d <<= 1) tm = fmaxf(tm, __shfl_xor(tm, d, 64));
            float mn = fmaxf(mj[j], tm);
            float corr = __expf((mj[j] - mn) * SCALE);
            mj[j] = mn;
            lj[j] *= corr;
            o0[j] *= corr; o1[j] *= corr;
            float p0 = __expf((s0[j] - mn) * SCALE);
            float p1 = __expf((s1[j] - mn) * SCALE);
            float p2 = __expf((s2[j] - mn) * SCALE);
            float p3 = __expf((s3[j] - mn) * SCALE);
            float ps = (p0 + p1) + (p2 + p3);
            #pragma unroll
            for (int d = 1; d < 16; d <<= 1) ps += __shfl_xor(ps, d, 64);
            lj[j] += ps;
            int row = hi * 4 + j;
            Pl[wid][row][ 0 + lo] = f2bf(p0);
            Pl[wid][row][16 + lo] = f2bf(p1);
            Pl[wid][row][32 + lo] = f2bf(p2);
            Pl[wid][row][48 + lo] = f2bf(p3);
        }

        // PV: O(16x32) += P(16x64) @ V(64x32)
        short8 pa0 = *(const short8*)&Pl[wid][lo][hi * 8];
        short8 pa1 = *(const short8*)&Pl[wid][lo][32 + hi * 8];
        short8 vb00 = *(const short8*)&Vt[ 0 + lo][ 0 + hi * 8];
        short8 vb10 = *(const short8*)&Vt[ 0 + lo][32 + hi * 8];
        short8 vb01 = *(const short8*)&Vt[16 + lo][ 0 + hi * 8];
        short8 vb11 = *(const short8*)&Vt[16 + lo][32 + hi * 8];
        o0 = __builtin_amdgcn_mfma_f32_16x16x32_bf16(pa0, vb00, o0, 0, 0, 0);
        o0 = __builtin_amdgcn_mfma_f32_16x16x32_bf16(pa1, vb10, o0, 0, 0, 0);
        o1 = __builtin_amdgcn_mfma_f32_16x16x32_bf16(pa0, vb01, o1, 0, 0, 0);
        o1 = __builtin_amdgcn_mfma_f32_16x16x32_bf16(pa1, vb11, o1, 0, 0, 0);
    }

    int b = bh >> 3, h = bh & 7;
    #pragma unroll
    for (int j = 0; j < 4; ++j) {
        float inv = 1.f / lj[j];
        long row = (long)b * N_ + q0 + hi * 4 + j;
        o[row * D_ + h * DH_ +  0 + lo] = o0[j] * inv;
        o[row * D_ + h * DH_ + 16 + lo] = o1[j] * inv;
    }
}

// ---------------- fused residual add + LayerNorm (row = 256, wave per row) ---
__global__ __launch_bounds__(256) void add_ln_kernel(
    float* __restrict__ h, const float* __restrict__ r,
    const float* __restrict__ g, const float* __restrict__ be)
{
    int row = blockIdx.x * 4 + (threadIdx.x >> 6);
    int lane = threadIdx.x & 63;
    long off = (long)row * D_ + (lane << 2);
    float4 x = *(float4*)&h[off];
    float4 rr = *(const float4*)&r[off];
    x.x += rr.x; x.y += rr.y; x.z += rr.z; x.w += rr.w;
    float s = x.x + x.y + x.z + x.w;
    #pragma unroll
    for (int k = 1; k < 64; k <<= 1) s += __shfl_xor(s, k, 64);
    float mean = s * (1.f / 256.f);
    float dx = x.x - mean, dy = x.y - mean, dz = x.z - mean, dw = x.w - mean;
    float sq = dx * dx + dy * dy + dz * dz + dw * dw;
    #pragma unroll
    for (int k = 1; k < 64; k <<= 1) sq += __shfl_xor(sq, k, 64);
    float rstd = rsqrtf(sq * (1.f / 256.f) + 1e-5f);
    float4 gv = *(const float4*)&g[lane << 2];
    float4 bv = *(const float4*)&be[lane << 2];
    float4 o;
    o.x = dx * rstd * gv.x + bv.x;
    o.y = dy * rstd * gv.y + bv.y;
    o.z = dz * rstd * gv.z + bv.z;
    o.w = dw * rstd * gv.w + bv.w;
    *(float4*)&h[off] = o;
}

extern "C" void kernel_launch(void* const* d_in, const int* in_sizes, int n_in,
                              void* d_out, int out_size, void* d_ws, size_t ws_size,
                              hipStream_t stream) {
    const float* h_in    = (const float*)d_in[0];
    const float* pos     = (const float*)d_in[1];
    const float* proj_w  = (const float*)d_in[2];
    const float* proj_b  = (const float*)d_in[3];
    const float* qkv_w   = (const float*)d_in[4];
    const float* out_w   = (const float*)d_in[5];
    const float* out_b   = (const float*)d_in[6];
    const float* O_w     = (const float*)d_in[7];
    const float* O_b     = (const float*)d_in[8];
    const float* ffn1_w  = (const float*)d_in[9];
    const float* ffn1_b  = (const float*)d_in[10];
    const float* ffn2_w  = (const float*)d_in[11];
    const float* ffn2_b  = (const float*)d_in[12];
    const float* ln1_g   = (const float*)d_in[13];
    const float* ln1_b   = (const float*)d_in[14];
    const float* ln2_g   = (const float*)d_in[15];
    const float* ln2_b   = (const float*)d_in[16];
    const float* final_w = (const float*)d_in[17];
    float* out = (float*)d_out;

    float* ws  = (float*)d_ws;
    float* h   = ws;                 // 2,097,152
    float* qkv = h + 2097152;        // 6,291,456
    float* ao  = qkv + 6291456;      // 2,097,152
    float* t1  = ao + 2097152;       // 2,097,152
    float* t2  = t1 + 2097152;       // 4,194,304
    float* tab = t2 + 4194304;       //   262,144

    // bf16 Q/K/V overlap t1 + part of t2 (dead at those points in the layer)
    ushort_t* Qb = (ushort_t*)t1;
    ushort_t* Kb = Qb + 2097152;
    ushort_t* Vb = Kb + 2097152;

    const long M = (long)B_ * N_;    // 8192 rows

    proj_kernel<<<(M * 64) / 256, 256, 0, stream>>>(h_in, proj_w, proj_b, h);
    rope_table_kernel<<<(B_ * N_) / 256, 256, 0, stream>>>(pos, tab);

    for (int l = 0; l < L_; ++l) {
        // qkv = h @ qkv_w[l]   (8192x768, K=256, no bias)
        gemm_f32<<<dim3(768 / 64, M / 64), 256, 0, stream>>>(
            h, qkv_w + (long)l * D_ * 3 * D_, nullptr, qkv, M, 3 * D_, D_, 0);
        // RoPE + bf16 convert -> Qb, Kb, Vb
        rope_convert_kernel<<<(M * H_ * 16) / 256, 256, 0, stream>>>(qkv, tab, Qb, Kb, Vb);
        // MFMA flash attention -> ao
        attn_mfma<<<dim3(N_ / 64, B_ * H_), 256, 0, stream>>>(Qb, Kb, Vb, ao);
        // o @ out_w + out_b -> t1 (overwrites Qb/Kb region: dead now)
        gemm_f32<<<dim3(D_ / 64, M / 64), 256, 0, stream>>>(
            ao, out_w + (long)l * D_ * D_, out_b + (long)l * D_, t1, M, D_, D_, 1);
        // t1 @ O_w + O_b -> t2
        gemm_f32<<<dim3(D_ / 64, M / 64), 256, 0, stream>>>(
            t1, O_w + (long)l * D_ * D_, O_b + (long)l * D_, t2, M, D_, D_, 1);
        // h = LN(h + t2)
        add_ln_kernel<<<M / 4, 256, 0, stream>>>(
            h, t2, ln1_g + (long)l * D_, ln1_b + (long)l * D_);
        // ffn1: relu(h @ ffn1_w + b) -> t2 (8192x512)
        gemm_f32<<<dim3(512 / 64, M / 64), 256, 0, stream>>>(
            h, ffn1_w + (long)l * D_ * 2 * D_, ffn1_b + (long)l * 2 * D_, t2, M, 2 * D_, D_, 3);
        // ffn2: t2 @ ffn2_w + b -> t1
        gemm_f32<<<dim3(D_ / 64, M / 64), 256, 0, stream>>>(
            t2, ffn2_w + (long)l * 2 * D_ * D_, ffn2_b + (long)l * D_, t1, M, D_, 2 * D_, 1);
        // h = LN(h + t1)
        add_ln_kernel<<<M / 4, 256, 0, stream>>>(
            h, t1, ln2_g + (long)l * D_, ln2_b + (long)l * D_);
    }
    // final: h @ final_w -> out (no bias)
    gemm_f32<<<dim3(D_ / 64, M / 64), 256, 0, stream>>>(
        h, final_w, nullptr, out, M, D_, D_, 0);
}

// Round 3
// 741.829 us; speedup vs baseline: 4.9001x; 1.6800x over previous
//
#include <hip/hip_runtime.h>
#include <math.h>

#define B_ 4
#define N_ 2048
#define D_ 256
#define H_ 8
#define L_ 4
#define DH_ 32

typedef float f32x4 __attribute__((ext_vector_type(4)));
typedef short short8 __attribute__((ext_vector_type(8)));
typedef unsigned short ushort_t;
typedef ushort_t ushortx4 __attribute__((ext_vector_type(4)));
typedef ushort_t ushortx8 __attribute__((ext_vector_type(8)));

static __device__ __forceinline__ ushort_t f2bf(float x) {
    unsigned int u = __float_as_uint(x);
    unsigned int r = (u + 0x7fffu + ((u >> 16) & 1u)) >> 16;   // RNE
    return (ushort_t)r;
}

// ---------------- proj: h = h_in * proj_w + proj_b; writes fp32 h + bf16 hb --
__global__ __launch_bounds__(256) void proj_kernel(
    const float* __restrict__ hin, const float* __restrict__ w,
    const float* __restrict__ bias, float* __restrict__ hout,
    ushort_t* __restrict__ hb)
{
    long idx = (long)blockIdx.x * 256 + threadIdx.x;      // over B*N*64
    long bn = idx >> 6;
    int d4 = (int)(idx & 63) << 2;
    float hv = hin[bn];
    float4 wv = *(const float4*)&w[d4];
    float4 bv = *(const float4*)&bias[d4];
    float4 o;
    o.x = hv * wv.x + bv.x;
    o.y = hv * wv.y + bv.y;
    o.z = hv * wv.z + bv.z;
    o.w = hv * wv.w + bv.w;
    *(float4*)&hout[bn * D_ + d4] = o;
    ushortx4 ob;
    ob[0] = f2bf(o.x); ob[1] = f2bf(o.y); ob[2] = f2bf(o.z); ob[3] = f2bf(o.w);
    *(ushortx4*)&hb[bn * D_ + d4] = ob;
}

// ---------------- RoPE cos/sin table ----------------------------------------
__global__ __launch_bounds__(256) void rope_table_kernel(
    const float* __restrict__ pos, float* __restrict__ tab)
{
    int i = blockIdx.x * 256 + threadIdx.x;   // over B*N = 8192
    if (i >= B_ * N_) return;
    float t = pos[i * 2 + 0] * 64.0f;
    float x = pos[i * 2 + 1] * 64.0f;
    float* o = tab + (long)i * 32;
    const float log2_1e4_over8 = 13.28771237954945f / 8.0f;
    #pragma unroll
    for (int j = 0; j < 8; ++j) {
        float invf = exp2f(-(float)j * log2_1e4_over8);   // 10000^{-j/8}
        float st, ct, sx, cx;
        sincosf(t * invf, &st, &ct);
        sincosf(x * invf, &sx, &cx);
        o[j]      = ct;
        o[8 + j]  = st;
        o[16 + j] = cx;
        o[24 + j] = sx;
    }
}

// ---- RoPE + bf16 convert: qkv fp32 (B,N,3D) -> Qb,Kb (roped), Vb, head-major
__global__ __launch_bounds__(256) void rope_convert_kernel(
    const float* __restrict__ qkv, const float* __restrict__ tab,
    ushort_t* __restrict__ Qb, ushort_t* __restrict__ Kb, ushort_t* __restrict__ Vb)
{
    long idx = (long)blockIdx.x * 256 + threadIdx.x;  // B*N*H*16 = 2097152
    int p = (int)(idx & 15);
    int h = (int)((idx >> 4) & 7);
    long bn = idx >> 7;
    int half = p >> 3;
    int j = p & 7;
    const float* tb = tab + bn * 32;
    float c = tb[half * 16 + j];
    float s = tb[half * 16 + 8 + j];
    int b = (int)(bn >> 11);
    int n = (int)(bn & 2047);
    long obase = ((long)(b * H_ + h) * N_ + n) * DH_;
    const float* base = qkv + bn * (3 * D_) + h * DH_ + half * 16 + j;
    int d0 = half * 16 + j;
    float q0 = base[0], q1 = base[8];
    Qb[obase + d0]     = f2bf(q0 * c - q1 * s);
    Qb[obase + d0 + 8] = f2bf(q1 * c + q0 * s);
    float k0 = base[D_], k1 = base[D_ + 8];
    Kb[obase + d0]     = f2bf(k0 * c - k1 * s);
    Kb[obase + d0 + 8] = f2bf(k1 * c + k0 * s);
    const float* vb = qkv + bn * (3 * D_) + 2 * D_ + h * DH_;
    Vb[obase + p]      = f2bf(vb[p]);
    Vb[obase + p + 16] = f2bf(vb[p + 16]);
}

// ---- weight prep: fp32 W[K][N] -> bf16 WT[N][K], all matrices, one launch ---
__global__ __launch_bounds__(256) void wprep_kernel(
    const float* __restrict__ qkv_w, const float* __restrict__ out_w,
    const float* __restrict__ O_w, const float* __restrict__ ffn1_w,
    const float* __restrict__ ffn2_w, const float* __restrict__ final_w,
    ushort_t* __restrict__ WT)
{
    int bid = blockIdx.x;
    const float* src; ushort_t* dst; int K, Nn, tile;
    if (bid < 192)      { int l = bid / 48;        tile = bid % 48;        src = qkv_w  + (long)l * 196608; dst = WT + (long)l * 196608;           K = 256; Nn = 768; }
    else if (bid < 256) { int r = bid - 192; int l = r / 16; tile = r % 16; src = out_w  + (long)l * 65536;  dst = WT + 786432  + (long)l * 65536;  K = 256; Nn = 256; }
    else if (bid < 320) { int r = bid - 256; int l = r / 16; tile = r % 16; src = O_w    + (long)l * 65536;  dst = WT + 1048576 + (long)l * 65536;  K = 256; Nn = 256; }
    else if (bid < 448) { int r = bid - 320; int l = r / 32; tile = r % 32; src = ffn1_w + (long)l * 131072; dst = WT + 1310720 + (long)l * 131072; K = 256; Nn = 512; }
    else if (bid < 576) { int r = bid - 448; int l = r / 32; tile = r % 32; src = ffn2_w + (long)l * 131072; dst = WT + 1835008 + (long)l * 131072; K = 512; Nn = 256; }
    else                { tile = bid - 576;                                 src = final_w;                   dst = WT + 2359296;                    K = 256; Nn = 256; }
    int ntn = Nn >> 6;
    int kt = (tile / ntn) << 6;
    int nt = (tile % ntn) << 6;
    __shared__ float Tl[64][65];
    int t = threadIdx.x;
    int kr = t >> 2, nc0 = (t & 3) << 4;
    const float* sp = src + (long)(kt + kr) * Nn + nt + nc0;
    float4 v0 = ((const float4*)sp)[0];
    float4 v1 = ((const float4*)sp)[1];
    float4 v2 = ((const float4*)sp)[2];
    float4 v3 = ((const float4*)sp)[3];
    float* tr = &Tl[kr][nc0];
    tr[0] = v0.x; tr[1] = v0.y; tr[2] = v0.z; tr[3] = v0.w;
    tr[4] = v1.x; tr[5] = v1.y; tr[6] = v1.z; tr[7] = v1.w;
    tr[8] = v2.x; tr[9] = v2.y; tr[10] = v2.z; tr[11] = v2.w;
    tr[12] = v3.x; tr[13] = v3.y; tr[14] = v3.z; tr[15] = v3.w;
    __syncthreads();
    int n = t >> 2, kc0 = (t & 3) << 4;
    ushortx8 o0, o1;
    #pragma unroll
    for (int i = 0; i < 8; ++i) o0[i] = f2bf(Tl[kc0 + i][n]);
    #pragma unroll
    for (int i = 0; i < 8; ++i) o1[i] = f2bf(Tl[kc0 + 8 + i][n]);
    ushort_t* dp = dst + (long)(nt + n) * K + kt + kc0;
    *(ushortx8*)dp = o0;
    *(ushortx8*)(dp + 8) = o1;
}

// ---------------- bf16 MFMA GEMM: C = A[M][K] @ WT[N][K]^T -------------------
// 64x64 tile, BK=64, 256 threads (4 waves 2x2). XOR-swizzled LDS, reg-staged.
// flags: 1=bias, 2=relu, 4=bf16 output
__global__ __launch_bounds__(256) void gemm_mfma(
    const ushort_t* __restrict__ A, const ushort_t* __restrict__ BT,
    const float* __restrict__ bias, void* __restrict__ Cout,
    int N, int K, int flags)
{
    __shared__ ushort_t sA[64 * 64];
    __shared__ ushort_t sB[64 * 64];
    int tid = threadIdx.x;
    int wid = tid >> 6, lane = tid & 63;
    int lo = lane & 15, hi = lane >> 4;
    int wm = wid >> 1, wn = wid & 1;
    int m0 = blockIdx.y << 6, n0 = blockIdx.x << 6;

    int srow = tid >> 3;          // 0..31
    int sslot = tid & 7;
    const ushort_t* Ap  = A  + (long)(m0 + srow) * K + sslot * 8;
    const ushort_t* Ap2 = Ap + 32 * (long)K;
    const ushort_t* Bp  = BT + (long)(n0 + srow) * K + sslot * 8;
    const ushort_t* Bp2 = Bp + 32 * (long)K;
    int wa1 = srow * 64 + (sslot ^ (srow & 7)) * 8;
    int wa2 = (srow + 32) * 64 + (sslot ^ (srow & 7)) * 8;   // (srow+32)&7 == srow&7

    f32x4 acc[2][2];
    #pragma unroll
    for (int i = 0; i < 2; ++i)
        #pragma unroll
        for (int j = 0; j < 2; ++j) acc[i][j] = (f32x4){0.f, 0.f, 0.f, 0.f};

    int ar0 = (wm * 32 + lo) * 64;        // A frag row base (mf=0)
    int ar1 = (wm * 32 + 16 + lo) * 64;   // mf=1
    int br0 = (wn * 32 + lo) * 64;
    int br1 = (wn * 32 + 16 + lo) * 64;
    int swz = lo & 7;

    for (int kt = 0; kt < K; kt += 64) {
        ushortx8 a1 = *(const ushortx8*)(Ap + kt);
        ushortx8 a2 = *(const ushortx8*)(Ap2 + kt);
        ushortx8 b1 = *(const ushortx8*)(Bp + kt);
        ushortx8 b2 = *(const ushortx8*)(Bp2 + kt);
        __syncthreads();
        *(ushortx8*)&sA[wa1] = a1;
        *(ushortx8*)&sA[wa2] = a2;
        *(ushortx8*)&sB[wa1] = b1;
        *(ushortx8*)&sB[wa2] = b2;
        __syncthreads();
        #pragma unroll
        for (int kf = 0; kf < 2; ++kf) {
            int ks = ((kf * 4 + hi) ^ swz) * 8;
            short8 a0 = *(const short8*)&sA[ar0 + ks];
            short8 a1f = *(const short8*)&sA[ar1 + ks];
            short8 b0 = *(const short8*)&sB[br0 + ks];
            short8 b1f = *(const short8*)&sB[br1 + ks];
            acc[0][0] = __builtin_amdgcn_mfma_f32_16x16x32_bf16(a0, b0, acc[0][0], 0, 0, 0);
            acc[0][1] = __builtin_amdgcn_mfma_f32_16x16x32_bf16(a0, b1f, acc[0][1], 0, 0, 0);
            acc[1][0] = __builtin_amdgcn_mfma_f32_16x16x32_bf16(a1f, b0, acc[1][0], 0, 0, 0);
            acc[1][1] = __builtin_amdgcn_mfma_f32_16x16x32_bf16(a1f, b1f, acc[1][1], 0, 0, 0);
        }
    }

    #pragma unroll
    for (int nf = 0; nf < 2; ++nf) {
        int col = n0 + wn * 32 + nf * 16 + lo;
        float bv = (flags & 1) ? bias[col] : 0.f;
        #pragma unroll
        for (int mf = 0; mf < 2; ++mf) {
            #pragma unroll
            for (int j = 0; j < 4; ++j) {
                float v = acc[mf][nf][j] + bv;
                if (flags & 2) v = fmaxf(v, 0.f);
                long row = m0 + wm * 32 + mf * 16 + hi * 4 + j;
                if (flags & 4) ((ushort_t*)Cout)[row * N + col] = f2bf(v);
                else           ((float*)Cout)[row * N + col] = v;
            }
        }
    }
}

// ---------------- MFMA flash attention, bf16 in/out, fp32 softmax/accum ------
__global__ __launch_bounds__(256) void attn_mfma(
    const ushort_t* __restrict__ Qb, const ushort_t* __restrict__ Kb,
    const ushort_t* __restrict__ Vb, ushort_t* __restrict__ o)
{
    const float SCALE = 0.17677669529663687f;   // 1/sqrt(32)
    int bh = blockIdx.y;
    int tid = threadIdx.x;
    int wid = tid >> 6, lane = tid & 63;
    int lo = lane & 15, hi = lane >> 4;
    int q0 = blockIdx.x * 64 + wid * 16;

    __shared__ ushort_t Vt[DH_][72];        // V transposed (dh, key), padded
    __shared__ ushort_t Pl[4][16][72];      // per-wave P (qrow, key), padded

    const ushort_t* Qbase = Qb + (long)bh * N_ * DH_;
    const ushort_t* Kbase = Kb + (long)bh * N_ * DH_;
    const ushort_t* Vbase = Vb + (long)bh * N_ * DH_;

    short8 qf = *(const short8*)&Qbase[(long)(q0 + lo) * DH_ + hi * 8];

    float mj[4], lj[4];
    f32x4 o0 = {0.f, 0.f, 0.f, 0.f}, o1 = {0.f, 0.f, 0.f, 0.f};
    #pragma unroll
    for (int j = 0; j < 4; ++j) { mj[j] = -1e30f; lj[j] = 0.f; }

    int vkey = tid & 63, vdh0 = (tid >> 6) * 8;

    for (int k0 = 0; k0 < N_; k0 += 64) {
        __syncthreads();
        {
            short8 vv = *(const short8*)&Vbase[(long)(k0 + vkey) * DH_ + vdh0];
            #pragma unroll
            for (int jj = 0; jj < 8; ++jj) Vt[vdh0 + jj][vkey] = (ushort_t)vv[jj];
        }
        __syncthreads();

        f32x4 zz = {0.f, 0.f, 0.f, 0.f};
        short8 kf0 = *(const short8*)&Kbase[(long)(k0 +  0 + lo) * DH_ + hi * 8];
        short8 kf1 = *(const short8*)&Kbase[(long)(k0 + 16 + lo) * DH_ + hi * 8];
        short8 kf2 = *(const short8*)&Kbase[(long)(k0 + 32 + lo) * DH_ + hi * 8];
        short8 kf3 = *(const short8*)&Kbase[(long)(k0 + 48 + lo) * DH_ + hi * 8];
        f32x4 s0 = __builtin_amdgcn_mfma_f32_16x16x32_bf16(qf, kf0, zz, 0, 0, 0);
        f32x4 s1 = __builtin_amdgcn_mfma_f32_16x16x32_bf16(qf, kf1, zz, 0, 0, 0);
        f32x4 s2 = __builtin_amdgcn_mfma_f32_16x16x32_bf16(qf, kf2, zz, 0, 0, 0);
        f32x4 s3 = __builtin_amdgcn_mfma_f32_16x16x32_bf16(qf, kf3, zz, 0, 0, 0);

        #pragma unroll
        for (int j = 0; j < 4; ++j) {
            float tm = fmaxf(fmaxf(s0[j], s1[j]), fmaxf(s2[j], s3[j]));
            #pragma unroll
            for (int d = 1; d < 16; d <<= 1) tm = fmaxf(tm, __shfl_xor(tm, d, 64));
            float mn = fmaxf(mj[j], tm);
            float corr = __expf((mj[j] - mn) * SCALE);
            mj[j] = mn;
            lj[j] *= corr;
            o0[j] *= corr; o1[j] *= corr;
            float p0 = __expf((s0[j] - mn) * SCALE);
            float p1 = __expf((s1[j] - mn) * SCALE);
            float p2 = __expf((s2[j] - mn) * SCALE);
            float p3 = __expf((s3[j] - mn) * SCALE);
            float ps = (p0 + p1) + (p2 + p3);
            #pragma unroll
            for (int d = 1; d < 16; d <<= 1) ps += __shfl_xor(ps, d, 64);
            lj[j] += ps;
            int row = hi * 4 + j;
            Pl[wid][row][ 0 + lo] = f2bf(p0);
            Pl[wid][row][16 + lo] = f2bf(p1);
            Pl[wid][row][32 + lo] = f2bf(p2);
            Pl[wid][row][48 + lo] = f2bf(p3);
        }

        short8 pa0 = *(const short8*)&Pl[wid][lo][hi * 8];
        short8 pa1 = *(const short8*)&Pl[wid][lo][32 + hi * 8];
        short8 vb00 = *(const short8*)&Vt[ 0 + lo][ 0 + hi * 8];
        short8 vb10 = *(const short8*)&Vt[ 0 + lo][32 + hi * 8];
        short8 vb01 = *(const short8*)&Vt[16 + lo][ 0 + hi * 8];
        short8 vb11 = *(const short8*)&Vt[16 + lo][32 + hi * 8];
        o0 = __builtin_amdgcn_mfma_f32_16x16x32_bf16(pa0, vb00, o0, 0, 0, 0);
        o0 = __builtin_amdgcn_mfma_f32_16x16x32_bf16(pa1, vb10, o0, 0, 0, 0);
        o1 = __builtin_amdgcn_mfma_f32_16x16x32_bf16(pa0, vb01, o1, 0, 0, 0);
        o1 = __builtin_amdgcn_mfma_f32_16x16x32_bf16(pa1, vb11, o1, 0, 0, 0);
    }

    int b = bh >> 3, h = bh & 7;
    #pragma unroll
    for (int j = 0; j < 4; ++j) {
        float inv = 1.f / lj[j];
        long row = (long)b * N_ + q0 + hi * 4 + j;
        o[row * D_ + h * DH_ +  0 + lo] = f2bf(o0[j] * inv);
        o[row * D_ + h * DH_ + 16 + lo] = f2bf(o1[j] * inv);
    }
}

// ---------------- fused residual add + LayerNorm; writes fp32 h + bf16 hb ----
__global__ __launch_bounds__(256) void add_ln_kernel(
    float* __restrict__ h, const float* __restrict__ r,
    const float* __restrict__ g, const float* __restrict__ be,
    ushort_t* __restrict__ hb)
{
    int row = blockIdx.x * 4 + (threadIdx.x >> 6);
    int lane = threadIdx.x & 63;
    long off = (long)row * D_ + (lane << 2);
    float4 x = *(float4*)&h[off];
    float4 rr = *(const float4*)&r[off];
    x.x += rr.x; x.y += rr.y; x.z += rr.z; x.w += rr.w;
    float s = x.x + x.y + x.z + x.w;
    #pragma unroll
    for (int k = 1; k < 64; k <<= 1) s += __shfl_xor(s, k, 64);
    float mean = s * (1.f / 256.f);
    float dx = x.x - mean, dy = x.y - mean, dz = x.z - mean, dw = x.w - mean;
    float sq = dx * dx + dy * dy + dz * dz + dw * dw;
    #pragma unroll
    for (int k = 1; k < 64; k <<= 1) sq += __shfl_xor(sq, k, 64);
    float rstd = rsqrtf(sq * (1.f / 256.f) + 1e-5f);
    float4 gv = *(const float4*)&g[lane << 2];
    float4 bv = *(const float4*)&be[lane << 2];
    float4 o;
    o.x = dx * rstd * gv.x + bv.x;
    o.y = dy * rstd * gv.y + bv.y;
    o.z = dz * rstd * gv.z + bv.z;
    o.w = dw * rstd * gv.w + bv.w;
    *(float4*)&h[off] = o;
    ushortx4 ob;
    ob[0] = f2bf(o.x); ob[1] = f2bf(o.y); ob[2] = f2bf(o.z); ob[3] = f2bf(o.w);
    *(ushortx4*)&hb[off] = ob;
}

extern "C" void kernel_launch(void* const* d_in, const int* in_sizes, int n_in,
                              void* d_out, int out_size, void* d_ws, size_t ws_size,
                              hipStream_t stream) {
    const float* h_in    = (const float*)d_in[0];
    const float* pos     = (const float*)d_in[1];
    const float* proj_w  = (const float*)d_in[2];
    const float* proj_b  = (const float*)d_in[3];
    const float* qkv_w   = (const float*)d_in[4];
    const float* out_w   = (const float*)d_in[5];
    const float* out_b   = (const float*)d_in[6];
    const float* O_w     = (const float*)d_in[7];
    const float* O_b     = (const float*)d_in[8];
    const float* ffn1_w  = (const float*)d_in[9];
    const float* ffn1_b  = (const float*)d_in[10];
    const float* ffn2_w  = (const float*)d_in[11];
    const float* ffn2_b  = (const float*)d_in[12];
    const float* ln1_g   = (const float*)d_in[13];
    const float* ln1_b   = (const float*)d_in[14];
    const float* ln2_g   = (const float*)d_in[15];
    const float* ln2_b   = (const float*)d_in[16];
    const float* final_w = (const float*)d_in[17];
    float* out = (float*)d_out;

    float* ws   = (float*)d_ws;
    float* h    = ws;                    // 2,097,152 f
    float* hb_f = h + 2097152;           // 1,048,576 f (bf16 h)
    float* tab  = hb_f + 1048576;        //   262,144 f
    float* WT_f = tab + 262144;          // 1,212,416 f (bf16 weights^T)
    float* R    = WT_f + 1212416;        // 6,291,456 f (qkv fp32, later temps)
    float* QKV  = R + 6291456;           // 3,145,728 f (Qb,Kb,Vb bf16)
    float* tf   = QKV + 3145728;         // 2,097,152 f (fp32 temp)

    ushort_t* hb  = (ushort_t*)hb_f;
    ushort_t* WT  = (ushort_t*)WT_f;
    float*    qkvf = R;
    ushort_t* aob = (ushort_t*)R;                    // after rope: qkv dead
    ushort_t* t1b = (ushort_t*)(R + 1048576);
    ushort_t* fb  = (ushort_t*)(R + 2097152);
    ushort_t* Qb  = (ushort_t*)QKV;
    ushort_t* Kb  = Qb + 2097152;
    ushort_t* Vb  = Kb + 2097152;

    // WT offsets (bf16 elems)
    const long qkvT_off  = 0;        // l*196608
    const long outT_off  = 786432;   // +l*65536
    const long OT_off    = 1048576;  // +l*65536
    const long ffn1T_off = 1310720;  // +l*131072
    const long ffn2T_off = 1835008;  // +l*131072
    const long finT_off  = 2359296;

    const long M = (long)B_ * N_;    // 8192 rows

    wprep_kernel<<<592, 256, 0, stream>>>(qkv_w, out_w, O_w, ffn1_w, ffn2_w, final_w, WT);
    proj_kernel<<<(M * 64) / 256, 256, 0, stream>>>(h_in, proj_w, proj_b, h, hb);
    rope_table_kernel<<<(B_ * N_) / 256, 256, 0, stream>>>(pos, tab);

    for (int l = 0; l < L_; ++l) {
        // qkv = hb @ qkv_w[l] -> fp32 qkvf   (N=768, K=256)
        gemm_mfma<<<dim3(768 / 64, M / 64), 256, 0, stream>>>(
            hb, WT + qkvT_off + (long)l * 196608, nullptr, qkvf, 768, 256, 0);
        // RoPE + bf16 convert -> Qb, Kb, Vb
        rope_convert_kernel<<<(M * H_ * 16) / 256, 256, 0, stream>>>(qkvf, tab, Qb, Kb, Vb);
        // MFMA flash attention -> aob (bf16; overwrites dead qkv region)
        attn_mfma<<<dim3(N_ / 64, B_ * H_), 256, 0, stream>>>(Qb, Kb, Vb, aob);
        // aob @ out_w + out_b -> t1b (bf16)  (N=256, K=256)
        gemm_mfma<<<dim3(256 / 64, M / 64), 256, 0, stream>>>(
            aob, WT + outT_off + (long)l * 65536, out_b + (long)l * D_, t1b, 256, 256, 1 | 4);
        // t1b @ O_w + O_b -> tf (fp32)
        gemm_mfma<<<dim3(256 / 64, M / 64), 256, 0, stream>>>(
            t1b, WT + OT_off + (long)l * 65536, O_b + (long)l * D_, tf, 256, 256, 1);
        // h = LN(h + tf) -> h, hb
        add_ln_kernel<<<M / 4, 256, 0, stream>>>(
            h, tf, ln1_g + (long)l * D_, ln1_b + (long)l * D_, hb);
        // ffn1: relu(hb @ ffn1_w + b) -> fb (bf16)  (N=512, K=256)
        gemm_mfma<<<dim3(512 / 64, M / 64), 256, 0, stream>>>(
            hb, WT + ffn1T_off + (long)l * 131072, ffn1_b + (long)l * 2 * D_, fb, 512, 256, 1 | 2 | 4);
        // ffn2: fb @ ffn2_w + b -> tf (fp32)  (N=256, K=512)
        gemm_mfma<<<dim3(256 / 64, M / 64), 256, 0, stream>>>(
            fb, WT + ffn2T_off + (long)l * 131072, ffn2_b + (long)l * D_, tf, 256, 512, 1);
        // h = LN(h + tf) -> h, hb
        add_ln_kernel<<<M / 4, 256, 0, stream>>>(
            h, tf, ln2_g + (long)l * D_, ln2_b + (long)l * D_, hb);
    }
    // final: hb @ final_w -> out (fp32, no bias)
    gemm_mfma<<<dim3(256 / 64, M / 64), 256, 0, stream>>>(
        hb, WT + finT_off, nullptr, out, 256, 256, 0);
}

// Round 4
// 565.253 us; speedup vs baseline: 6.4308x; 1.3124x over previous
//
#include <hip/hip_runtime.h>
#include <math.h>

#define B_ 4
#define N_ 2048
#define D_ 256
#define H_ 8
#define L_ 4
#define DH_ 32

typedef float f32x4 __attribute__((ext_vector_type(4)));
typedef short short8 __attribute__((ext_vector_type(8)));
typedef unsigned short ushort_t;
typedef ushort_t ushortx4 __attribute__((ext_vector_type(4)));
typedef ushort_t ushortx8 __attribute__((ext_vector_type(8)));

static __device__ __forceinline__ ushort_t f2bf(float x) {
    unsigned int u = __float_as_uint(x);
    unsigned int r = (u + 0x7fffu + ((u >> 16) & 1u)) >> 16;   // RNE
    return (ushort_t)r;
}

static __device__ __forceinline__ unsigned int cvt_pk_bf16(float a, float b) {
    unsigned int w;
    asm("v_cvt_pk_bf16_f32 %0, %1, %2" : "=v"(w) : "v"(a), "v"(b));
    return w;   // low 16 = a, high 16 = b
}

// ---------------- proj: h = h_in * proj_w + proj_b; writes fp32 h + bf16 hb --
__global__ __launch_bounds__(256) void proj_kernel(
    const float* __restrict__ hin, const float* __restrict__ w,
    const float* __restrict__ bias, float* __restrict__ hout,
    ushort_t* __restrict__ hb)
{
    long idx = (long)blockIdx.x * 256 + threadIdx.x;      // over B*N*64
    long bn = idx >> 6;
    int d4 = (int)(idx & 63) << 2;
    float hv = hin[bn];
    float4 wv = *(const float4*)&w[d4];
    float4 bv = *(const float4*)&bias[d4];
    float4 o;
    o.x = hv * wv.x + bv.x;
    o.y = hv * wv.y + bv.y;
    o.z = hv * wv.z + bv.z;
    o.w = hv * wv.w + bv.w;
    *(float4*)&hout[bn * D_ + d4] = o;
    ushortx4 ob;
    ob[0] = f2bf(o.x); ob[1] = f2bf(o.y); ob[2] = f2bf(o.z); ob[3] = f2bf(o.w);
    *(ushortx4*)&hb[bn * D_ + d4] = ob;
}

// ---------------- RoPE cos/sin table ----------------------------------------
__global__ __launch_bounds__(256) void rope_table_kernel(
    const float* __restrict__ pos, float* __restrict__ tab)
{
    int i = blockIdx.x * 256 + threadIdx.x;   // over B*N = 8192
    if (i >= B_ * N_) return;
    float t = pos[i * 2 + 0] * 64.0f;
    float x = pos[i * 2 + 1] * 64.0f;
    float* o = tab + (long)i * 32;
    const float log2_1e4_over8 = 13.28771237954945f / 8.0f;
    #pragma unroll
    for (int j = 0; j < 8; ++j) {
        float invf = exp2f(-(float)j * log2_1e4_over8);   // 10000^{-j/8}
        float st, ct, sx, cx;
        sincosf(t * invf, &st, &ct);
        sincosf(x * invf, &sx, &cx);
        o[j]      = ct;
        o[8 + j]  = st;
        o[16 + j] = cx;
        o[24 + j] = sx;
    }
}

// ---- RoPE + bf16 convert: Q (prescaled by 1/sqrt(dh)*log2e) and K, head-major
__global__ __launch_bounds__(256) void rope_convert_kernel(
    const float* __restrict__ qkv, const float* __restrict__ tab,
    ushort_t* __restrict__ Qb, ushort_t* __restrict__ Kb)
{
    const float F = 0.17677669529663687f * 1.4426950408889634f;  // scale * log2(e)
    long idx = (long)blockIdx.x * 256 + threadIdx.x;  // B*N*H*16 = 2097152
    int p = (int)(idx & 15);
    int h = (int)((idx >> 4) & 7);
    long bn = idx >> 7;
    int half = p >> 3;
    int j = p & 7;
    const float* tb = tab + bn * 32;
    float c = tb[half * 16 + j];
    float s = tb[half * 16 + 8 + j];
    float cF = c * F, sF = s * F;
    int b = (int)(bn >> 11);
    int n = (int)(bn & 2047);
    long obase = ((long)(b * H_ + h) * N_ + n) * DH_;
    const float* base = qkv + bn * (3 * D_) + h * DH_ + half * 16 + j;
    int d0 = half * 16 + j;
    float q0 = base[0], q1 = base[8];
    Qb[obase + d0]     = f2bf(q0 * cF - q1 * sF);
    Qb[obase + d0 + 8] = f2bf(q1 * cF + q0 * sF);
    float k0 = base[D_], k1 = base[D_ + 8];
    Kb[obase + d0]     = f2bf(k0 * c - k1 * s);
    Kb[obase + d0 + 8] = f2bf(k1 * c + k0 * s);
}

// ---- V transpose: qkv fp32 V section -> Vt_g bf16 [bh][32 dh][2048 n] -------
__global__ __launch_bounds__(256) void vtrans_kernel(
    const float* __restrict__ qkv, ushort_t* __restrict__ Vt)
{
    int bh = blockIdx.y;
    int b = bh >> 3, h = bh & 7;
    int n0 = blockIdx.x << 6;
    __shared__ float T[64][36];
    int t = threadIdx.x;
    int r = t >> 2, c0 = (t & 3) << 3;
    const float* src = qkv + ((long)b * N_ + n0 + r) * (3 * D_) + 2 * D_ + h * DH_ + c0;
    float4 a = ((const float4*)src)[0];
    float4 bb = ((const float4*)src)[1];
    *(float4*)&T[r][c0] = a;
    *(float4*)&T[r][c0 + 4] = bb;
    __syncthreads();
    int d = t >> 3, n8 = (t & 7) << 3;
    ushortx8 o;
    #pragma unroll
    for (int i = 0; i < 8; ++i) o[i] = f2bf(T[n8 + i][d]);
    *(ushortx8*)&Vt[((long)bh * DH_ + d) * N_ + n0 + n8] = o;
}

// ---- weight prep: fp32 W[K][N] -> bf16 WT[N][K], all matrices, one launch ---
__global__ __launch_bounds__(256) void wprep_kernel(
    const float* __restrict__ qkv_w, const float* __restrict__ out_w,
    const float* __restrict__ O_w, const float* __restrict__ ffn1_w,
    const float* __restrict__ ffn2_w, const float* __restrict__ final_w,
    ushort_t* __restrict__ WT)
{
    int bid = blockIdx.x;
    const float* src; ushort_t* dst; int K, Nn, tile;
    if (bid < 192)      { int l = bid / 48;        tile = bid % 48;        src = qkv_w  + (long)l * 196608; dst = WT + (long)l * 196608;           K = 256; Nn = 768; }
    else if (bid < 256) { int r = bid - 192; int l = r / 16; tile = r % 16; src = out_w  + (long)l * 65536;  dst = WT + 786432  + (long)l * 65536;  K = 256; Nn = 256; }
    else if (bid < 320) { int r = bid - 256; int l = r / 16; tile = r % 16; src = O_w    + (long)l * 65536;  dst = WT + 1048576 + (long)l * 65536;  K = 256; Nn = 256; }
    else if (bid < 448) { int r = bid - 320; int l = r / 32; tile = r % 32; src = ffn1_w + (long)l * 131072; dst = WT + 1310720 + (long)l * 131072; K = 256; Nn = 512; }
    else if (bid < 576) { int r = bid - 448; int l = r / 32; tile = r % 32; src = ffn2_w + (long)l * 131072; dst = WT + 1835008 + (long)l * 131072; K = 512; Nn = 256; }
    else                { tile = bid - 576;                                 src = final_w;                   dst = WT + 2359296;                    K = 256; Nn = 256; }
    int ntn = Nn >> 6;
    int kt = (tile / ntn) << 6;
    int nt = (tile % ntn) << 6;
    __shared__ float Tl[64][65];
    int t = threadIdx.x;
    int kr = t >> 2, nc0 = (t & 3) << 4;
    const float* sp = src + (long)(kt + kr) * Nn + nt + nc0;
    float4 v0 = ((const float4*)sp)[0];
    float4 v1 = ((const float4*)sp)[1];
    float4 v2 = ((const float4*)sp)[2];
    float4 v3 = ((const float4*)sp)[3];
    float* tr = &Tl[kr][nc0];
    tr[0] = v0.x; tr[1] = v0.y; tr[2] = v0.z; tr[3] = v0.w;
    tr[4] = v1.x; tr[5] = v1.y; tr[6] = v1.z; tr[7] = v1.w;
    tr[8] = v2.x; tr[9] = v2.y; tr[10] = v2.z; tr[11] = v2.w;
    tr[12] = v3.x; tr[13] = v3.y; tr[14] = v3.z; tr[15] = v3.w;
    __syncthreads();
    int n = t >> 2, kc0 = (t & 3) << 4;
    ushortx8 o0, o1;
    #pragma unroll
    for (int i = 0; i < 8; ++i) o0[i] = f2bf(Tl[kc0 + i][n]);
    #pragma unroll
    for (int i = 0; i < 8; ++i) o1[i] = f2bf(Tl[kc0 + 8 + i][n]);
    ushort_t* dp = dst + (long)(nt + n) * K + kt + kc0;
    *(ushortx8*)dp = o0;
    *(ushortx8*)(dp + 8) = o1;
}

// ---------------- bf16 MFMA GEMM: C = A[M][K] @ WT[N][K]^T -------------------
// 64x64 tile, BK=64, 256 threads (4 waves 2x2). XOR-swizzled LDS, reg-staged.
// flags: 1=bias, 2=relu, 4=bf16 output
__global__ __launch_bounds__(256) void gemm_mfma(
    const ushort_t* __restrict__ A, const ushort_t* __restrict__ BT,
    const float* __restrict__ bias, void* __restrict__ Cout,
    int N, int K, int flags)
{
    __shared__ ushort_t sA[64 * 64];
    __shared__ ushort_t sB[64 * 64];
    int tid = threadIdx.x;
    int wid = tid >> 6, lane = tid & 63;
    int lo = lane & 15, hi = lane >> 4;
    int wm = wid >> 1, wn = wid & 1;
    int m0 = blockIdx.y << 6, n0 = blockIdx.x << 6;

    int srow = tid >> 3;          // 0..31
    int sslot = tid & 7;
    const ushort_t* Ap  = A  + (long)(m0 + srow) * K + sslot * 8;
    const ushort_t* Ap2 = Ap + 32 * (long)K;
    const ushort_t* Bp  = BT + (long)(n0 + srow) * K + sslot * 8;
    const ushort_t* Bp2 = Bp + 32 * (long)K;
    int wa1 = srow * 64 + (sslot ^ (srow & 7)) * 8;
    int wa2 = (srow + 32) * 64 + (sslot ^ (srow & 7)) * 8;

    f32x4 acc[2][2];
    #pragma unroll
    for (int i = 0; i < 2; ++i)
        #pragma unroll
        for (int j = 0; j < 2; ++j) acc[i][j] = (f32x4){0.f, 0.f, 0.f, 0.f};

    int ar0 = (wm * 32 + lo) * 64;
    int ar1 = (wm * 32 + 16 + lo) * 64;
    int br0 = (wn * 32 + lo) * 64;
    int br1 = (wn * 32 + 16 + lo) * 64;
    int swz = lo & 7;

    for (int kt = 0; kt < K; kt += 64) {
        ushortx8 a1 = *(const ushortx8*)(Ap + kt);
        ushortx8 a2 = *(const ushortx8*)(Ap2 + kt);
        ushortx8 b1 = *(const ushortx8*)(Bp + kt);
        ushortx8 b2 = *(const ushortx8*)(Bp2 + kt);
        __syncthreads();
        *(ushortx8*)&sA[wa1] = a1;
        *(ushortx8*)&sA[wa2] = a2;
        *(ushortx8*)&sB[wa1] = b1;
        *(ushortx8*)&sB[wa2] = b2;
        __syncthreads();
        #pragma unroll
        for (int kf = 0; kf < 2; ++kf) {
            int ks = ((kf * 4 + hi) ^ swz) * 8;
            short8 a0 = *(const short8*)&sA[ar0 + ks];
            short8 a1f = *(const short8*)&sA[ar1 + ks];
            short8 b0 = *(const short8*)&sB[br0 + ks];
            short8 b1f = *(const short8*)&sB[br1 + ks];
            acc[0][0] = __builtin_amdgcn_mfma_f32_16x16x32_bf16(a0, b0, acc[0][0], 0, 0, 0);
            acc[0][1] = __builtin_amdgcn_mfma_f32_16x16x32_bf16(a0, b1f, acc[0][1], 0, 0, 0);
            acc[1][0] = __builtin_amdgcn_mfma_f32_16x16x32_bf16(a1f, b0, acc[1][0], 0, 0, 0);
            acc[1][1] = __builtin_amdgcn_mfma_f32_16x16x32_bf16(a1f, b1f, acc[1][1], 0, 0, 0);
        }
    }

    #pragma unroll
    for (int nf = 0; nf < 2; ++nf) {
        int col = n0 + wn * 32 + nf * 16 + lo;
        float bv = (flags & 1) ? bias[col] : 0.f;
        #pragma unroll
        for (int mf = 0; mf < 2; ++mf) {
            #pragma unroll
            for (int j = 0; j < 4; ++j) {
                float v = acc[mf][nf][j] + bv;
                if (flags & 2) v = fmaxf(v, 0.f);
                long row = m0 + wm * 32 + mf * 16 + hi * 4 + j;
                if (flags & 4) ((ushort_t*)Cout)[row * N + col] = f2bf(v);
                else           ((float*)Cout)[row * N + col] = v;
            }
        }
    }
}

// ---------------- swapped-QK^T MFMA flash attention --------------------------
// grid (N/64, B*H), 256 thr (4 waves, 16 q each). 128-key iters, exp2 domain.
// Q pre-scaled by SCALE*log2e. V pre-transposed [bh][dh][n].
__global__ __launch_bounds__(256) void attn_mfma2(
    const ushort_t* __restrict__ Qb, const ushort_t* __restrict__ Kb,
    const ushort_t* __restrict__ Vt, ushort_t* __restrict__ o)
{
    int bh = blockIdx.y;
    int tid = threadIdx.x;
    int wid = tid >> 6, lane = tid & 63;
    int lo = lane & 15, hi = lane >> 4;
    int q0 = (blockIdx.x << 6) + wid * 16;

    __shared__ ushort_t Vl[2][32][136];     // [buf][dh][key], 272B rows
    __shared__ ushort_t Pl[4][16][136];     // per-wave P [q][key]

    const ushort_t* Qbase = Qb + (long)bh * N_ * DH_;
    const ushort_t* Kbase = Kb + (long)bh * N_ * DH_;
    const ushort_t* Vbase = Vt + (long)bh * DH_ * N_;   // [32][2048]

    short8 qf = *(const short8*)&Qbase[(long)(q0 + lo) * DH_ + hi * 8];

    // V staging map: thread covers rows (tid>>4) and (tid>>4)+16, 8 keys each
    int vrow = tid >> 4;           // 0..15
    int vc8 = (tid & 15) << 3;     // 0..120

    // prologue: stage tile 0
    {
        short8 v0 = *(const short8*)&Vbase[(long)vrow * N_ + vc8];
        short8 v1 = *(const short8*)&Vbase[(long)(vrow + 16) * N_ + vc8];
        *(short8*)&Vl[0][vrow][vc8] = v0;
        *(short8*)&Vl[0][vrow + 16][vc8] = v1;
    }
    __syncthreads();

    float m = -1e30f, l = 0.f;
    f32x4 acc0 = {0.f, 0.f, 0.f, 0.f}, acc1 = {0.f, 0.f, 0.f, 0.f};

    for (int it = 0; it < N_ / 128; ++it) {
        int k0 = it << 7;
        int buf = it & 1;
        // prefetch next V tile to regs
        short8 nv0, nv1;
        if (it < N_ / 128 - 1) {
            nv0 = *(const short8*)&Vbase[(long)vrow * N_ + k0 + 128 + vc8];
            nv1 = *(const short8*)&Vbase[(long)(vrow + 16) * N_ + k0 + 128 + vc8];
        }
        // S^T = K Q^T : 8 tiles of 16 keys
        f32x4 s[8];
        const f32x4 zz = {0.f, 0.f, 0.f, 0.f};
        #pragma unroll
        for (int t = 0; t < 8; ++t) {
            short8 kf = *(const short8*)&Kbase[(long)(k0 + 16 * t + lo) * DH_ + hi * 8];
            s[t] = __builtin_amdgcn_mfma_f32_16x16x32_bf16(kf, qf, zz, 0, 0, 0);
        }
        // in-lane max over 32 + cross-hi reduce
        f32x4 m4 = s[0];
        #pragma unroll
        for (int t = 1; t < 8; ++t) {
            m4[0] = fmaxf(m4[0], s[t][0]); m4[1] = fmaxf(m4[1], s[t][1]);
            m4[2] = fmaxf(m4[2], s[t][2]); m4[3] = fmaxf(m4[3], s[t][3]);
        }
        float pmax = fmaxf(fmaxf(m4[0], m4[1]), fmaxf(m4[2], m4[3]));
        pmax = fmaxf(pmax, __shfl_xor(pmax, 16, 64));
        pmax = fmaxf(pmax, __shfl_xor(pmax, 32, 64));
        // defer-max rescale (THR=8 in log2 units)
        if (!__all(pmax <= m + 8.f)) {
            float mn = fmaxf(m, pmax);
            float corr = __builtin_amdgcn_exp2f(m - mn);
            m = mn;
            l *= corr;
            acc0 *= corr;
            acc1 *= corr;
        }
        // p = exp2(s - m)
        #pragma unroll
        for (int t = 0; t < 8; ++t) {
            s[t][0] = __builtin_amdgcn_exp2f(s[t][0] - m);
            s[t][1] = __builtin_amdgcn_exp2f(s[t][1] - m);
            s[t][2] = __builtin_amdgcn_exp2f(s[t][2] - m);
            s[t][3] = __builtin_amdgcn_exp2f(s[t][3] - m);
        }
        // row sum (in-lane + cross-hi)
        f32x4 sv = s[0];
        #pragma unroll
        for (int t = 1; t < 8; ++t) sv += s[t];
        float sum = (sv[0] + sv[1]) + (sv[2] + sv[3]);
        sum += __shfl_xor(sum, 16, 64);
        sum += __shfl_xor(sum, 32, 64);
        l += sum;
        // pack to bf16 words, write to wave-private P (no barrier needed)
        {
            unsigned int* Pw = (unsigned int*)&Pl[wid][lo][0];
            #pragma unroll
            for (int t = 0; t < 8; ++t) {
                Pw[8 * t + 2 * hi]     = cvt_pk_bf16(s[t][0], s[t][1]);
                Pw[8 * t + 2 * hi + 1] = cvt_pk_bf16(s[t][2], s[t][3]);
            }
        }
        // stage next V tile into other buffer (prev-iter barrier protects it)
        if (it < N_ / 128 - 1) {
            *(short8*)&Vl[buf ^ 1][vrow][vc8] = nv0;
            *(short8*)&Vl[buf ^ 1][vrow + 16][vc8] = nv1;
        }
        // PV: O(16q x 32d) += P(16q x 128k) @ V(128k x 32d)
        #pragma unroll
        for (int c = 0; c < 4; ++c) {
            short8 pa  = *(const short8*)&Pl[wid][lo][32 * c + 8 * hi];
            short8 vb0 = *(const short8*)&Vl[buf][lo][32 * c + 8 * hi];
            short8 vb1 = *(const short8*)&Vl[buf][16 + lo][32 * c + 8 * hi];
            acc0 = __builtin_amdgcn_mfma_f32_16x16x32_bf16(pa, vb0, acc0, 0, 0, 0);
            acc1 = __builtin_amdgcn_mfma_f32_16x16x32_bf16(pa, vb1, acc1, 0, 0, 0);
        }
        __syncthreads();
    }

    // epilogue: normalize and store (q = 4*hi + j per output row)
    float invl = 1.f / l;       // valid for q = lo
    int b = bh >> 3, h = bh & 7;
    #pragma unroll
    for (int j = 0; j < 4; ++j) {
        float iv = __shfl(invl, 4 * hi + j, 64);
        long row = (long)b * N_ + q0 + 4 * hi + j;
        o[row * D_ + h * DH_ + lo]      = f2bf(acc0[j] * iv);
        o[row * D_ + h * DH_ + 16 + lo] = f2bf(acc1[j] * iv);
    }
}

// ---------------- fused residual add + LayerNorm; writes fp32 h + bf16 hb ----
__global__ __launch_bounds__(256) void add_ln_kernel(
    float* __restrict__ h, const float* __restrict__ r,
    const float* __restrict__ g, const float* __restrict__ be,
    ushort_t* __restrict__ hb)
{
    int row = blockIdx.x * 4 + (threadIdx.x >> 6);
    int lane = threadIdx.x & 63;
    long off = (long)row * D_ + (lane << 2);
    float4 x = *(float4*)&h[off];
    float4 rr = *(const float4*)&r[off];
    x.x += rr.x; x.y += rr.y; x.z += rr.z; x.w += rr.w;
    float s = x.x + x.y + x.z + x.w;
    #pragma unroll
    for (int k = 1; k < 64; k <<= 1) s += __shfl_xor(s, k, 64);
    float mean = s * (1.f / 256.f);
    float dx = x.x - mean, dy = x.y - mean, dz = x.z - mean, dw = x.w - mean;
    float sq = dx * dx + dy * dy + dz * dz + dw * dw;
    #pragma unroll
    for (int k = 1; k < 64; k <<= 1) sq += __shfl_xor(sq, k, 64);
    float rstd = rsqrtf(sq * (1.f / 256.f) + 1e-5f);
    float4 gv = *(const float4*)&g[lane << 2];
    float4 bv = *(const float4*)&be[lane << 2];
    float4 o;
    o.x = dx * rstd * gv.x + bv.x;
    o.y = dy * rstd * gv.y + bv.y;
    o.z = dz * rstd * gv.z + bv.z;
    o.w = dw * rstd * gv.w + bv.w;
    *(float4*)&h[off] = o;
    ushortx4 ob;
    ob[0] = f2bf(o.x); ob[1] = f2bf(o.y); ob[2] = f2bf(o.z); ob[3] = f2bf(o.w);
    *(ushortx4*)&hb[off] = ob;
}

extern "C" void kernel_launch(void* const* d_in, const int* in_sizes, int n_in,
                              void* d_out, int out_size, void* d_ws, size_t ws_size,
                              hipStream_t stream) {
    const float* h_in    = (const float*)d_in[0];
    const float* pos     = (const float*)d_in[1];
    const float* proj_w  = (const float*)d_in[2];
    const float* proj_b  = (const float*)d_in[3];
    const float* qkv_w   = (const float*)d_in[4];
    const float* out_w   = (const float*)d_in[5];
    const float* out_b   = (const float*)d_in[6];
    const float* O_w     = (const float*)d_in[7];
    const float* O_b     = (const float*)d_in[8];
    const float* ffn1_w  = (const float*)d_in[9];
    const float* ffn1_b  = (const float*)d_in[10];
    const float* ffn2_w  = (const float*)d_in[11];
    const float* ffn2_b  = (const float*)d_in[12];
    const float* ln1_g   = (const float*)d_in[13];
    const float* ln1_b   = (const float*)d_in[14];
    const float* ln2_g   = (const float*)d_in[15];
    const float* ln2_b   = (const float*)d_in[16];
    const float* final_w = (const float*)d_in[17];
    float* out = (float*)d_out;

    float* ws   = (float*)d_ws;
    float* h    = ws;                    // 2,097,152 f
    float* hb_f = h + 2097152;           // 1,048,576 f (bf16 h)
    float* tab  = hb_f + 1048576;        //   262,144 f
    float* WT_f = tab + 262144;          // 1,212,416 f (bf16 weights^T)
    float* R    = WT_f + 1212416;        // 6,291,456 f (qkv fp32, later temps)
    float* QKV  = R + 6291456;           // 3,145,728 f (Qb,Kb,Vt bf16)
    float* tf   = QKV + 3145728;         // 2,097,152 f (fp32 temp)

    ushort_t* hb  = (ushort_t*)hb_f;
    ushort_t* WT  = (ushort_t*)WT_f;
    float*    qkvf = R;
    ushort_t* aob = (ushort_t*)R;                    // after vtrans: qkv dead
    ushort_t* t1b = (ushort_t*)(R + 1048576);
    ushort_t* fb  = (ushort_t*)(R + 2097152);
    ushort_t* Qb  = (ushort_t*)QKV;
    ushort_t* Kb  = Qb + 2097152;
    ushort_t* Vtg = Kb + 2097152;

    const long qkvT_off  = 0;
    const long outT_off  = 786432;
    const long OT_off    = 1048576;
    const long ffn1T_off = 1310720;
    const long ffn2T_off = 1835008;
    const long finT_off  = 2359296;

    const long M = (long)B_ * N_;    // 8192 rows

    wprep_kernel<<<592, 256, 0, stream>>>(qkv_w, out_w, O_w, ffn1_w, ffn2_w, final_w, WT);
    proj_kernel<<<(M * 64) / 256, 256, 0, stream>>>(h_in, proj_w, proj_b, h, hb);
    rope_table_kernel<<<(B_ * N_) / 256, 256, 0, stream>>>(pos, tab);

    for (int l = 0; l < L_; ++l) {
        // qkv = hb @ qkv_w[l] -> fp32 qkvf   (N=768, K=256)
        gemm_mfma<<<dim3(768 / 64, M / 64), 256, 0, stream>>>(
            hb, WT + qkvT_off + (long)l * 196608, nullptr, qkvf, 768, 256, 0);
        // RoPE + bf16 convert (Q prescaled) -> Qb, Kb
        rope_convert_kernel<<<(M * H_ * 16) / 256, 256, 0, stream>>>(qkvf, tab, Qb, Kb);
        // V transpose -> Vtg [bh][dh][n]
        vtrans_kernel<<<dim3(N_ / 64, B_ * H_), 256, 0, stream>>>(qkvf, Vtg);
        // swapped-QK^T flash attention -> aob (bf16)
        attn_mfma2<<<dim3(N_ / 64, B_ * H_), 256, 0, stream>>>(Qb, Kb, Vtg, aob);
        // aob @ out_w + out_b -> t1b (bf16)  (N=256, K=256)
        gemm_mfma<<<dim3(256 / 64, M / 64), 256, 0, stream>>>(
            aob, WT + outT_off + (long)l * 65536, out_b + (long)l * D_, t1b, 256, 256, 1 | 4);
        // t1b @ O_w + O_b -> tf (fp32)
        gemm_mfma<<<dim3(256 / 64, M / 64), 256, 0, stream>>>(
            t1b, WT + OT_off + (long)l * 65536, O_b + (long)l * D_, tf, 256, 256, 1);
        // h = LN(h + tf) -> h, hb
        add_ln_kernel<<<M / 4, 256, 0, stream>>>(
            h, tf, ln1_g + (long)l * D_, ln1_b + (long)l * D_, hb);
        // ffn1: relu(hb @ ffn1_w + b) -> fb (bf16)  (N=512, K=256)
        gemm_mfma<<<dim3(512 / 64, M / 64), 256, 0, stream>>>(
            hb, WT + ffn1T_off + (long)l * 131072, ffn1_b + (long)l * 2 * D_, fb, 512, 256, 1 | 2 | 4);
        // ffn2: fb @ ffn2_w + b -> tf (fp32)  (N=256, K=512)
        gemm_mfma<<<dim3(256 / 64, M / 64), 256, 0, stream>>>(
            fb, WT + ffn2T_off + (long)l * 131072, ffn2_b + (long)l * D_, tf, 256, 512, 1);
        // h = LN(h + tf) -> h, hb
        add_ln_kernel<<<M / 4, 256, 0, stream>>>(
            h, tf, ln2_g + (long)l * D_, ln2_b + (long)l * D_, hb);
    }
    // final: hb @ final_w -> out (fp32, no bias)
    gemm_mfma<<<dim3(256 / 64, M / 64), 256, 0, stream>>>(
        hb, WT + finT_off, nullptr, out, 256, 256, 0);
}